// Round 1
// baseline (2998.565 us; speedup 1.0000x reference)
//
#include <hip/hip_runtime.h>
#include <cstddef>

#define S    2048
#define EDIM 1024
#define NH   16
#define DH   64
#define BATCH 2

// ---------------------------------------------------------------------------
// NT GEMM core: C[m,n] = sum_k A[m,k] * B[n,k]  (A row-major MxK, B row-major NxK)
// 64x64 tile, BK=16, 256 threads as 16x16, each thread computes 4x4 (stride-16).
// ---------------------------------------------------------------------------

__global__ __launch_bounds__(256) void qkv_gemm_kernel(
    const float* __restrict__ A,    // x [4096][1024]
    const float* __restrict__ Bw,   // qkv_w [3072][1024]
    const float* __restrict__ bias, // [3072]
    float* __restrict__ Qb, float* __restrict__ Kb, float* __restrict__ Vb)
{
  __shared__ __align__(16) float As[64][20];
  __shared__ __align__(16) float Bs[64][20];
  const int t  = threadIdx.x;
  const int tx = t & 15, ty = t >> 4;
  const int m0 = blockIdx.x * 64;
  const int n0 = blockIdx.y * 64;
  const int arow = t >> 2;
  const int ac   = (t & 3) << 2;

  float acc[4][4];
#pragma unroll
  for (int i = 0; i < 4; ++i)
#pragma unroll
    for (int j = 0; j < 4; ++j) acc[i][j] = 0.f;

  for (int kt = 0; kt < 64; ++kt) {
    const float4 av = *(const float4*)&A [(size_t)(m0 + arow) * 1024 + kt * 16 + ac];
    const float4 bv = *(const float4*)&Bw[(size_t)(n0 + arow) * 1024 + kt * 16 + ac];
    __syncthreads();
    *(float4*)&As[arow][ac] = av;
    *(float4*)&Bs[arow][ac] = bv;
    __syncthreads();
#pragma unroll
    for (int k = 0; k < 16; k += 4) {
      float4 a4[4], b4[4];
#pragma unroll
      for (int i = 0; i < 4; ++i) a4[i] = *(const float4*)&As[16 * i + ty][k];
#pragma unroll
      for (int j = 0; j < 4; ++j) b4[j] = *(const float4*)&Bs[16 * j + tx][k];
#pragma unroll
      for (int i = 0; i < 4; ++i)
#pragma unroll
        for (int j = 0; j < 4; ++j)
          acc[i][j] += a4[i].x * b4[j].x + a4[i].y * b4[j].y +
                       a4[i].z * b4[j].z + a4[i].w * b4[j].w;
    }
  }

  // epilogue: scatter into per-head Q/K/V [B][H][S][D]
  const int part = n0 >> 10;             // constant per block (n0 multiple of 64)
  const int h    = (n0 >> 6) & 15;       // constant per block
  float* dst = (part == 0) ? Qb : (part == 1) ? Kb : Vb;
#pragma unroll
  for (int i = 0; i < 4; ++i) {
    const int m  = m0 + 16 * i + ty;
    const int bi = m >> 11;
    const int s  = m & 2047;
#pragma unroll
    for (int j = 0; j < 4; ++j) {
      const int n = n0 + 16 * j + tx;
      const int d = n & 63;
      dst[((size_t)(bi * NH + h) * S + s) * DH + d] = acc[i][j] + bias[n];
    }
  }
}

__global__ __launch_bounds__(256) void out_gemm_kernel(
    const float* __restrict__ A,    // attn_out [4096][1024]  (B,S,H,D flattened)
    const float* __restrict__ Bw,   // out_w [1024][1024]
    const float* __restrict__ bias, // [1024]
    float* __restrict__ C)          // output [4096][1024]
{
  __shared__ __align__(16) float As[64][20];
  __shared__ __align__(16) float Bs[64][20];
  const int t  = threadIdx.x;
  const int tx = t & 15, ty = t >> 4;
  const int m0 = blockIdx.x * 64;
  const int n0 = blockIdx.y * 64;
  const int arow = t >> 2;
  const int ac   = (t & 3) << 2;

  float acc[4][4];
#pragma unroll
  for (int i = 0; i < 4; ++i)
#pragma unroll
    for (int j = 0; j < 4; ++j) acc[i][j] = 0.f;

  for (int kt = 0; kt < 64; ++kt) {
    const float4 av = *(const float4*)&A [(size_t)(m0 + arow) * 1024 + kt * 16 + ac];
    const float4 bv = *(const float4*)&Bw[(size_t)(n0 + arow) * 1024 + kt * 16 + ac];
    __syncthreads();
    *(float4*)&As[arow][ac] = av;
    *(float4*)&Bs[arow][ac] = bv;
    __syncthreads();
#pragma unroll
    for (int k = 0; k < 16; k += 4) {
      float4 a4[4], b4[4];
#pragma unroll
      for (int i = 0; i < 4; ++i) a4[i] = *(const float4*)&As[16 * i + ty][k];
#pragma unroll
      for (int j = 0; j < 4; ++j) b4[j] = *(const float4*)&Bs[16 * j + tx][k];
#pragma unroll
      for (int i = 0; i < 4; ++i)
#pragma unroll
        for (int j = 0; j < 4; ++j)
          acc[i][j] += a4[i].x * b4[j].x + a4[i].y * b4[j].y +
                       a4[i].z * b4[j].z + a4[i].w * b4[j].w;
    }
  }

#pragma unroll
  for (int i = 0; i < 4; ++i) {
    const int m = m0 + 16 * i + ty;
#pragma unroll
    for (int j = 0; j < 4; ++j) {
      const int n = n0 + 16 * j + tx;
      C[(size_t)m * EDIM + n] = acc[i][j] + bias[n];
    }
  }
}

// ---------------------------------------------------------------------------
// Fused attention per (b,h,q-tile of 64). Pass 1: online row max/sum.
// Pass 2: recompute scores, write softmax weights to global, accumulate P*V.
// ---------------------------------------------------------------------------

__global__ __launch_bounds__(256) void attn_kernel(
    const float* __restrict__ Qb, const float* __restrict__ Kb,
    const float* __restrict__ Vb,
    float* __restrict__ Pw,   // attn_weights [B*H][S][S]
    float* __restrict__ AO)   // attn_out [B][S][H][D]
{
  __shared__ __align__(16) float Qs[64][68];
  __shared__ __align__(16) float Ks[64][68];
  __shared__ __align__(16) float Vs[64][68];
  __shared__ __align__(16) float Ps[64][68];
  __shared__ float redm[64][17];
  __shared__ float redl[64][17];
  __shared__ float Ms[64];
  __shared__ float Li[64];

  const int t  = threadIdx.x;
  const int tx = t & 15, ty = t >> 4;
  const int bh = blockIdx.x >> 5;   // 32 q-tiles per (b,h)
  const int qt = blockIdx.x & 31;
  const int q0 = qt * 64;
  const float* Qp = Qb + (size_t)bh * S * DH;
  const float* Kp = Kb + (size_t)bh * S * DH;
  const float* Vp = Vb + (size_t)bh * S * DH;
  float* Pp = Pw + (size_t)bh * S * S + (size_t)q0 * S;
  const int bi = bh >> 4, h = bh & 15;
  const float scale = 0.125f;  // 1/sqrt(64)

  // load Q tile [64][64]
#pragma unroll
  for (int it = 0; it < 4; ++it) {
    const int f = t + 256 * it;
    const int row = f >> 4, c = (f & 15) << 2;
    *(float4*)&Qs[row][c] = *(const float4*)&Qp[(size_t)(q0 + row) * DH + c];
  }

  float mt[4], lt[4];
#pragma unroll
  for (int i = 0; i < 4; ++i) { mt[i] = -1e30f; lt[i] = 0.f; }

  // ---------------- pass 1: row max + sum (online) ----------------
  for (int kt = 0; kt < 32; ++kt) {
    float4 kreg[4];
#pragma unroll
    for (int it = 0; it < 4; ++it) {
      const int f = t + 256 * it;
      const int row = f >> 4, c = (f & 15) << 2;
      kreg[it] = *(const float4*)&Kp[(size_t)(kt * 64 + row) * DH + c];
    }
    __syncthreads();
#pragma unroll
    for (int it = 0; it < 4; ++it) {
      const int f = t + 256 * it;
      const int row = f >> 4, c = (f & 15) << 2;
      *(float4*)&Ks[row][c] = kreg[it];
    }
    __syncthreads();

    float sc[4][4];
#pragma unroll
    for (int i = 0; i < 4; ++i)
#pragma unroll
      for (int j = 0; j < 4; ++j) sc[i][j] = 0.f;
#pragma unroll
    for (int e = 0; e < 64; e += 4) {
      float4 q4[4], k4[4];
#pragma unroll
      for (int i = 0; i < 4; ++i) q4[i] = *(const float4*)&Qs[16 * i + ty][e];
#pragma unroll
      for (int j = 0; j < 4; ++j) k4[j] = *(const float4*)&Ks[16 * j + tx][e];
#pragma unroll
      for (int i = 0; i < 4; ++i)
#pragma unroll
        for (int j = 0; j < 4; ++j)
          sc[i][j] += q4[i].x * k4[j].x + q4[i].y * k4[j].y +
                      q4[i].z * k4[j].z + q4[i].w * k4[j].w;
    }
#pragma unroll
    for (int i = 0; i < 4; ++i) {
      const float s0 = sc[i][0] * scale, s1 = sc[i][1] * scale;
      const float s2 = sc[i][2] * scale, s3 = sc[i][3] * scale;
      const float mloc = fmaxf(fmaxf(s0, s1), fmaxf(s2, s3));
      const float mnew = fmaxf(mt[i], mloc);
      lt[i] = lt[i] * expf(mt[i] - mnew) +
              expf(s0 - mnew) + expf(s1 - mnew) + expf(s2 - mnew) + expf(s3 - mnew);
      mt[i] = mnew;
    }
  }

  // reduce (m,l) across the 16 tx-threads of each row
#pragma unroll
  for (int i = 0; i < 4; ++i) {
    redm[16 * i + ty][tx] = mt[i];
    redl[16 * i + ty][tx] = lt[i];
  }
  __syncthreads();
  if (t < 64) {
    float m = -1e30f;
    for (int x2 = 0; x2 < 16; ++x2) m = fmaxf(m, redm[t][x2]);
    float l = 0.f;
    for (int x2 = 0; x2 < 16; ++x2) l += redl[t][x2] * expf(redm[t][x2] - m);
    Ms[t] = m;
    Li[t] = 1.0f / l;
  }
  __syncthreads();

  float mrow[4], lrow[4];
#pragma unroll
  for (int i = 0; i < 4; ++i) {
    mrow[i] = Ms[16 * i + ty];
    lrow[i] = Li[16 * i + ty];
  }

  float o[4][4];
#pragma unroll
  for (int i = 0; i < 4; ++i)
#pragma unroll
    for (int j = 0; j < 4; ++j) o[i][j] = 0.f;

  // ---------------- pass 2: recompute scores, emit P, accumulate P*V --------
  for (int kt = 0; kt < 32; ++kt) {
    float4 kreg[4], vreg[4];
#pragma unroll
    for (int it = 0; it < 4; ++it) {
      const int f = t + 256 * it;
      const int row = f >> 4, c = (f & 15) << 2;
      kreg[it] = *(const float4*)&Kp[(size_t)(kt * 64 + row) * DH + c];
      vreg[it] = *(const float4*)&Vp[(size_t)(kt * 64 + row) * DH + c];
    }
    __syncthreads();   // previous PV done using Ks/Vs/Ps
#pragma unroll
    for (int it = 0; it < 4; ++it) {
      const int f = t + 256 * it;
      const int row = f >> 4, c = (f & 15) << 2;
      *(float4*)&Ks[row][c] = kreg[it];
      *(float4*)&Vs[row][c] = vreg[it];
    }
    __syncthreads();

    float sc[4][4];
#pragma unroll
    for (int i = 0; i < 4; ++i)
#pragma unroll
      for (int j = 0; j < 4; ++j) sc[i][j] = 0.f;
#pragma unroll
    for (int e = 0; e < 64; e += 4) {
      float4 q4[4], k4[4];
#pragma unroll
      for (int i = 0; i < 4; ++i) q4[i] = *(const float4*)&Qs[16 * i + ty][e];
#pragma unroll
      for (int j = 0; j < 4; ++j) k4[j] = *(const float4*)&Ks[16 * j + tx][e];
#pragma unroll
      for (int i = 0; i < 4; ++i)
#pragma unroll
        for (int j = 0; j < 4; ++j)
          sc[i][j] += q4[i].x * k4[j].x + q4[i].y * k4[j].y +
                      q4[i].z * k4[j].z + q4[i].w * k4[j].w;
    }

#pragma unroll
    for (int i = 0; i < 4; ++i) {
#pragma unroll
      for (int j = 0; j < 4; ++j) {
        const float p = expf(sc[i][j] * scale - mrow[i]) * lrow[i];
        Ps[16 * i + ty][16 * j + tx] = p;
        Pp[(size_t)(16 * i + ty) * S + kt * 64 + 16 * j + tx] = p;
      }
    }
    __syncthreads();

    // o[i][j] += sum_k Ps[16i+ty][k] * Vs[k][4*tx+j]
#pragma unroll
    for (int k = 0; k < 64; k += 4) {
      float4 p4[4], v4[4];
#pragma unroll
      for (int i = 0; i < 4; ++i) p4[i] = *(const float4*)&Ps[16 * i + ty][k];
#pragma unroll
      for (int kk = 0; kk < 4; ++kk) v4[kk] = *(const float4*)&Vs[k + kk][4 * tx];
#pragma unroll
      for (int i = 0; i < 4; ++i) {
        o[i][0] += p4[i].x * v4[0].x + p4[i].y * v4[1].x + p4[i].z * v4[2].x + p4[i].w * v4[3].x;
        o[i][1] += p4[i].x * v4[0].y + p4[i].y * v4[1].y + p4[i].z * v4[2].y + p4[i].w * v4[3].y;
        o[i][2] += p4[i].x * v4[0].z + p4[i].y * v4[1].z + p4[i].z * v4[2].z + p4[i].w * v4[3].z;
        o[i][3] += p4[i].x * v4[0].w + p4[i].y * v4[1].w + p4[i].z * v4[2].w + p4[i].w * v4[3].w;
      }
    }
  }

  // write attn_out in [B][S][H][D] layout (== [B,S,E] for the out projection)
#pragma unroll
  for (int i = 0; i < 4; ++i) {
    float4 ov;
    ov.x = o[i][0]; ov.y = o[i][1]; ov.z = o[i][2]; ov.w = o[i][3];
    *(float4*)&AO[((size_t)(bi * S + q0 + 16 * i + ty) * NH + h) * DH + 4 * tx] = ov;
  }
}

// ---------------------------------------------------------------------------

extern "C" void kernel_launch(void* const* d_in, const int* in_sizes, int n_in,
                              void* d_out, int out_size, void* d_ws, size_t ws_size,
                              hipStream_t stream) {
  (void)in_sizes; (void)n_in; (void)out_size; (void)ws_size;
  const float* x     = (const float*)d_in[0];
  const float* qkv_w = (const float*)d_in[1];
  const float* qkv_b = (const float*)d_in[2];
  const float* out_w = (const float*)d_in[3];
  const float* out_b = (const float*)d_in[4];

  float* out  = (float*)d_out;                                   // [B,S,E]
  float* attw = out + (size_t)BATCH * S * EDIM;                  // [B,H,S,S]

  float* w  = (float*)d_ws;
  float* Qb = w;                 // [B,H,S,D] = 4,194,304 floats
  float* Kb = w + 4194304;
  float* Vb = w + 8388608;
  float* AO = w + 12582912;      // [B,S,H,D]

  qkv_gemm_kernel<<<dim3(64, 48), 256, 0, stream>>>(x, qkv_w, qkv_b, Qb, Kb, Vb);
  attn_kernel<<<dim3(1024), 256, 0, stream>>>(Qb, Kb, Vb, attw, AO);
  out_gemm_kernel<<<dim3(64, 16), 256, 0, stream>>>(AO, out_w, out_b, out);
}